// Round 3
// baseline (724.958 us; speedup 1.0000x reference)
//
#include <hip/hip_runtime.h>

// MemN2N: B=64, S=4096, D=256, hops=3 (fp32).
// Algebraic reduction: softmax over a size-1 axis == 1 -> attention weights
// are the memory-validity mask, hop-independent:
//   x_b = sum_{s < len_b - 1} sentences[b,s,:]
//   out_b = q0_b + hops sequential adds of (x_b @ W)
// Single fused kernel: block (c,b) self-computes len_b, column-sums its row
// chunk, publishes an ordered partial; the 32nd-arriving block per b
// (device-scope atomic counter) combines partials + GEMV + epilogue.
// Deterministic summation order (no float atomics).

#define BN 64
#define SN 4096
#define DN 256
#define CHUNKS 32
#define CHUNK_ROWS (SN / CHUNKS) // 128

__global__ __launch_bounds__(256)
void k_fused(const float* __restrict__ sent,
             const unsigned int* __restrict__ mask_words,
             const float* __restrict__ Wm,
             const int* __restrict__ hops_ptr,
             float* __restrict__ partials,        // ws: [BN][CHUNKS][DN]
             unsigned int* __restrict__ counters, // ws: [BN], memset to 0
             float* __restrict__ out) {
    const int c = blockIdx.x;
    const int b = blockIdx.y;
    const int t = threadIdx.x;

    __shared__ int lred[4];
    __shared__ int len_sh;
    __shared__ float4 red[256];
    __shared__ float xs[DN];
    __shared__ int flag_sh;

    // ---- per-block length recompute (mask row: 4 KB, L2-hot) ----
    // dtype detect from word 0 (len>=2 => first two elements true):
    //   1 -> int32 0/1; 0x3f800000 -> f32 1.0 (defensive); else bool bytes.
    const unsigned int w0 = mask_words[0];
    const int mode = (w0 == 1u) ? 0 : (w0 == 0x3f800000u) ? 1 : 2;
    const int wpr = (mode == 2) ? (SN / 4) : SN;
    const unsigned int* mrow = mask_words + (size_t)b * wpr;
    int lsum = 0;
    for (int i = t; i < wpr; i += 256) {
        const unsigned int w = mrow[i];
        lsum += (mode == 2) ? __popc(w) : (mode == 0 ? (int)w : (w != 0u ? 1 : 0));
    }
    #pragma unroll
    for (int off = 32; off > 0; off >>= 1)
        lsum += __shfl_down(lsum, off, 64);
    if ((t & 63) == 0) lred[t >> 6] = lsum;
    __syncthreads();
    if (t == 0) len_sh = lred[0] + lred[1] + lred[2] + lred[3];
    __syncthreads();
    const int limit = len_sh - 1;                 // memory rows: s < limit

    // ---- chunk column-sum: rows [c*128, min((c+1)*128, limit)) ----
    const int s0 = c * CHUNK_ROWS;
    const int d4 = (t & 63) * 4;                  // 4 contiguous columns
    const int g = t >> 6;                         // row group 0..3
    float4 acc = make_float4(0.f, 0.f, 0.f, 0.f);
    int nrows = limit - s0;
    if (nrows > CHUNK_ROWS) nrows = CHUNK_ROWS;
    if (nrows > 0) {
        const float* base = sent + ((size_t)b * SN + s0) * DN + d4;
        #pragma unroll 4
        for (int r = g; r < nrows; r += 4) {
            const float4 v = *reinterpret_cast<const float4*>(base + (size_t)r * DN);
            acc.x += v.x; acc.y += v.y; acc.z += v.z; acc.w += v.w;
        }
    }
    red[t] = acc;
    __syncthreads();
    if (t < 64) {
        const float4 a0 = red[t], a1 = red[64 + t], a2 = red[128 + t], a3 = red[192 + t];
        float4 o;
        o.x = a0.x + a1.x + a2.x + a3.x;
        o.y = a0.y + a1.y + a2.y + a3.y;
        o.z = a0.z + a1.z + a2.z + a3.z;
        o.w = a0.w + a1.w + a2.w + a3.w;
        reinterpret_cast<float4*>(partials + ((size_t)b * CHUNKS + c) * DN)[t] = o;
    }
    __threadfence();                              // publish partial (device scope)
    __syncthreads();
    if (t == 0) {
        const unsigned int old = atomicAdd(&counters[b], 1u);
        flag_sh = (old == CHUNKS - 1) ? 1 : 0;    // last arriver finalizes b
    }
    __syncthreads();
    if (!flag_sh) return;

    // ---- finalizer: combine partials + GEMV + epilogue ----
    __threadfence();                              // acquire partials
    const int d = t;
    float x = 0.f;
    const float* p = partials + (size_t)b * CHUNKS * DN + d;
    #pragma unroll
    for (int k = 0; k < CHUNKS; ++k)
        x += p[k * DN];
    xs[d] = x;
    __syncthreads();
    const float q0 = sent[((size_t)b * SN + limit) * DN + d];
    float gv = 0.f;
    #pragma unroll 8
    for (int k = 0; k < DN; ++k)
        gv = fmaf(xs[k], Wm[k * DN + d], gv);
    const int hops = hops_ptr[0];
    float r = q0;
    for (int i = 0; i < hops; ++i)                // match reference add order
        r += gv;
    out[b * DN + d] = r;
}

extern "C" void kernel_launch(void* const* d_in, const int* in_sizes, int n_in,
                              void* d_out, int out_size, void* d_ws, size_t ws_size,
                              hipStream_t stream) {
    const float* sent = (const float*)d_in[0];
    const unsigned int* mask = (const unsigned int*)d_in[1];
    const float* Wm = (const float*)d_in[2];
    const int* hops = (const int*)d_in[3];
    float* out = (float*)d_out;

    // ws layout: [0,256) counters (64 u32); [1024, 1024+2MB) partials
    unsigned int* counters = (unsigned int*)d_ws;
    float* partials = (float*)((char*)d_ws + 1024);

    hipMemsetAsync(counters, 0, BN * sizeof(unsigned int), stream); // capturable
    k_fused<<<dim3(CHUNKS, BN), dim3(256), 0, stream>>>(
        sent, mask, Wm, hops, partials, counters, out);
}

// Round 4
// 355.326 us; speedup vs baseline: 2.0403x; 2.0403x over previous
//
#include <hip/hip_runtime.h>

// MemN2N: B=64, S=4096, D=256, hops=3 (fp32).
// Algebraic reduction: softmax over a size-1 axis == 1 -> attention weights
// are the memory-validity mask, hop-independent:
//   x_b = sum_{s < len_b - 1} sentences[b,s,:]
//   out_b = q0_b + hops sequential adds of (x_b @ W)
// Two kernels, no device-scope fences/atomics (round-3 lesson: 2 threadfences
// x 2048 blocks cost ~400 us in cross-XCD L2 writebacks):
//   k_colsum: block (c,b) self-computes len_b (4 KB mask row, L2-hot) and
//             column-sums its 128-row chunk into partials[b][c][:].
//   k_final : block b self-computes len_b, combines partials, GEMV, epilogue.

#define BN 64
#define SN 4096
#define DN 256
#define CHUNKS 32
#define CHUNK_ROWS (SN / CHUNKS) // 128

// Per-block valid-length compute. Mask dtype detected from word 0
// (len >= 2 guarantees first two elements are true):
//   1 -> int32 0/1; 0x3f800000 -> f32 1.0 (defensive); else bool bytes.
__device__ __forceinline__ int block_len(const unsigned int* __restrict__ mask_words,
                                         int b, int t, int* lred, int* len_sh) {
    const unsigned int w0 = mask_words[0];
    const int mode = (w0 == 1u) ? 0 : (w0 == 0x3f800000u) ? 1 : 2;
    const int wpr = (mode == 2) ? (SN / 4) : SN;
    const unsigned int* mrow = mask_words + (size_t)b * wpr;
    int lsum = 0;
    for (int i = t; i < wpr; i += 256) {
        const unsigned int w = mrow[i];
        lsum += (mode == 2) ? __popc(w) : (mode == 0 ? (int)w : (w != 0u ? 1 : 0));
    }
    #pragma unroll
    for (int off = 32; off > 0; off >>= 1)
        lsum += __shfl_down(lsum, off, 64);
    if ((t & 63) == 0) lred[t >> 6] = lsum;
    __syncthreads();
    if (t == 0) *len_sh = lred[0] + lred[1] + lred[2] + lred[3];
    __syncthreads();
    return *len_sh;
}

__global__ __launch_bounds__(256)
void k_colsum(const float* __restrict__ sent,
              const unsigned int* __restrict__ mask_words,
              float* __restrict__ partials) {      // [BN][CHUNKS][DN]
    const int c = blockIdx.x;
    const int b = blockIdx.y;
    const int t = threadIdx.x;
    __shared__ int lred[4];
    __shared__ int len_sh;
    __shared__ float4 red[256];

    const int limit = block_len(mask_words, b, t, lred, &len_sh) - 1;

    const int s0 = c * CHUNK_ROWS;
    const int d4 = (t & 63) * 4;                   // 4 contiguous columns
    const int g = t >> 6;                          // row group 0..3
    float4 acc = make_float4(0.f, 0.f, 0.f, 0.f);
    int nrows = limit - s0;
    if (nrows > CHUNK_ROWS) nrows = CHUNK_ROWS;
    if (nrows > 0) {
        const float* base = sent + ((size_t)b * SN + s0) * DN + d4;
        #pragma unroll 4
        for (int r = g; r < nrows; r += 4) {
            const float4 v = *reinterpret_cast<const float4*>(base + (size_t)r * DN);
            acc.x += v.x; acc.y += v.y; acc.z += v.z; acc.w += v.w;
        }
    }
    red[t] = acc;
    __syncthreads();
    if (t < 64) {
        const float4 a0 = red[t], a1 = red[64 + t], a2 = red[128 + t], a3 = red[192 + t];
        float4 o;
        o.x = a0.x + a1.x + a2.x + a3.x;
        o.y = a0.y + a1.y + a2.y + a3.y;
        o.z = a0.z + a1.z + a2.z + a3.z;
        o.w = a0.w + a1.w + a2.w + a3.w;
        reinterpret_cast<float4*>(partials + ((size_t)b * CHUNKS + c) * DN)[t] = o;
    }
}

__global__ __launch_bounds__(256)
void k_final(const float* __restrict__ sent,
             const unsigned int* __restrict__ mask_words,
             const float* __restrict__ Wm,
             const int* __restrict__ hops_ptr,
             const float* __restrict__ partials,
             float* __restrict__ out) {
    const int b = blockIdx.x;
    const int t = threadIdx.x;                     // == d, 256 threads
    __shared__ int lred[4];
    __shared__ int len_sh;
    __shared__ float xs[DN];

    const int limit = block_len(mask_words, b, t, lred, &len_sh) - 1;

    float x = 0.f;
    const float* p = partials + (size_t)b * CHUNKS * DN + t;
    #pragma unroll
    for (int k = 0; k < CHUNKS; ++k)
        x += p[k * DN];
    xs[t] = x;
    __syncthreads();
    const float q0 = sent[((size_t)b * SN + limit) * DN + t];
    float gv = 0.f;
    #pragma unroll 8
    for (int k = 0; k < DN; ++k)
        gv = fmaf(xs[k], Wm[k * DN + t], gv);
    const int hops = hops_ptr[0];
    float r = q0;
    for (int i = 0; i < hops; ++i)                 // match reference add order
        r += gv;
    out[b * DN + t] = r;
}

extern "C" void kernel_launch(void* const* d_in, const int* in_sizes, int n_in,
                              void* d_out, int out_size, void* d_ws, size_t ws_size,
                              hipStream_t stream) {
    const float* sent = (const float*)d_in[0];
    const unsigned int* mask = (const unsigned int*)d_in[1];
    const float* Wm = (const float*)d_in[2];
    const int* hops = (const int*)d_in[3];
    float* out = (float*)d_out;

    float* partials = (float*)d_ws;                // 2 MB of ws

    k_colsum<<<dim3(CHUNKS, BN), dim3(256), 0, stream>>>(sent, mask, partials);
    k_final<<<dim3(BN), dim3(256), 0, stream>>>(sent, mask, Wm, hops, partials, out);
}

// Round 5
// 354.539 us; speedup vs baseline: 2.0448x; 1.0022x over previous
//
#include <hip/hip_runtime.h>

// MemN2N: B=64, S=4096, D=256, hops=3 (fp32).
// Algebraic reduction: softmax over a size-1 axis == 1 -> attention weights
// are the memory-validity mask, hop-independent:
//   x_b = sum_{s < len_b - 1} sentences[b,s,:]
//   out_b = q0_b + hops sequential adds of (x_b @ W)
// Two kernels, no device-scope fences/atomics (round-3 lesson: fences x 2048
// blocks cost ~400 us). Round-4 lesson: with grid (c fast = blockIdx.x,
// b = blockIdx.y), CU-resident blocks all share the same chunk index c
// (ids i, i+256 differ by a multiple of 32) -> CUs with low c do 2x the mean
// work while high-c CUs early-exit. Fix: 1D grid with b as the FAST index so
// each CU's blocks span c = {c0, c0+4, ..., c0+28} -> balanced.

#define BN 64
#define SN 4096
#define DN 256
#define CHUNKS 32
#define CHUNK_ROWS (SN / CHUNKS) // 128

// Per-block valid-length compute. Mask dtype detected from word 0
// (len >= 2 guarantees first two elements are true):
//   1 -> int32 0/1; 0x3f800000 -> f32 1.0 (defensive); else bool bytes.
__device__ __forceinline__ int block_len(const unsigned int* __restrict__ mask_words,
                                         int b, int t, int* lred, int* len_sh) {
    const unsigned int w0 = mask_words[0];
    const int mode = (w0 == 1u) ? 0 : (w0 == 0x3f800000u) ? 1 : 2;
    const int wpr = (mode == 2) ? (SN / 4) : SN;
    const unsigned int* mrow = mask_words + (size_t)b * wpr;
    int lsum = 0;
    for (int i = t; i < wpr; i += 256) {
        const unsigned int w = mrow[i];
        lsum += (mode == 2) ? __popc(w) : (mode == 0 ? (int)w : (w != 0u ? 1 : 0));
    }
    #pragma unroll
    for (int off = 32; off > 0; off >>= 1)
        lsum += __shfl_down(lsum, off, 64);
    if ((t & 63) == 0) lred[t >> 6] = lsum;
    __syncthreads();
    if (t == 0) *len_sh = lred[0] + lred[1] + lred[2] + lred[3];
    __syncthreads();
    return *len_sh;
}

__global__ __launch_bounds__(256)
void k_colsum(const float* __restrict__ sent,
              const unsigned int* __restrict__ mask_words,
              float* __restrict__ partials) {      // [BN][CHUNKS][DN]
    const int id = blockIdx.x;                     // 1D: b fast, c slow
    const int b = id & (BN - 1);
    const int c = id >> 6;
    const int t = threadIdx.x;
    __shared__ int lred[4];
    __shared__ int len_sh;
    __shared__ float4 red[256];

    const int limit = block_len(mask_words, b, t, lred, &len_sh) - 1;

    const int s0 = c * CHUNK_ROWS;
    const int d4 = (t & 63) * 4;                   // 4 contiguous columns
    const int g = t >> 6;                          // row group 0..3
    float4 acc = make_float4(0.f, 0.f, 0.f, 0.f);
    int nrows = limit - s0;
    if (nrows > CHUNK_ROWS) nrows = CHUNK_ROWS;
    if (nrows > 0) {
        const float* base = sent + ((size_t)b * SN + s0) * DN + d4;
        #pragma unroll 4
        for (int r = g; r < nrows; r += 4) {
            const float4 v = *reinterpret_cast<const float4*>(base + (size_t)r * DN);
            acc.x += v.x; acc.y += v.y; acc.z += v.z; acc.w += v.w;
        }
    }
    red[t] = acc;
    __syncthreads();
    if (t < 64) {
        const float4 a0 = red[t], a1 = red[64 + t], a2 = red[128 + t], a3 = red[192 + t];
        float4 o;
        o.x = a0.x + a1.x + a2.x + a3.x;
        o.y = a0.y + a1.y + a2.y + a3.y;
        o.z = a0.z + a1.z + a2.z + a3.z;
        o.w = a0.w + a1.w + a2.w + a3.w;
        reinterpret_cast<float4*>(partials + ((size_t)b * CHUNKS + c) * DN)[t] = o;
    }
}

__global__ __launch_bounds__(256)
void k_final(const float* __restrict__ sent,
             const unsigned int* __restrict__ mask_words,
             const float* __restrict__ Wm,
             const int* __restrict__ hops_ptr,
             const float* __restrict__ partials,
             float* __restrict__ out) {
    const int b = blockIdx.x;
    const int t = threadIdx.x;                     // == d, 256 threads
    __shared__ int lred[4];
    __shared__ int len_sh;
    __shared__ float xs[DN];

    const int limit = block_len(mask_words, b, t, lred, &len_sh) - 1;

    float x = 0.f;
    const float* p = partials + (size_t)b * CHUNKS * DN + t;
    #pragma unroll
    for (int k = 0; k < CHUNKS; ++k)
        x += p[k * DN];
    xs[t] = x;
    __syncthreads();
    const float q0 = sent[((size_t)b * SN + limit) * DN + t];
    float gv = 0.f;
    #pragma unroll 8
    for (int k = 0; k < DN; ++k)
        gv = fmaf(xs[k], Wm[k * DN + t], gv);
    const int hops = hops_ptr[0];
    float r = q0;
    for (int i = 0; i < hops; ++i)                 // match reference add order
        r += gv;
    out[b * DN + t] = r;
}

extern "C" void kernel_launch(void* const* d_in, const int* in_sizes, int n_in,
                              void* d_out, int out_size, void* d_ws, size_t ws_size,
                              hipStream_t stream) {
    const float* sent = (const float*)d_in[0];
    const unsigned int* mask = (const unsigned int*)d_in[1];
    const float* Wm = (const float*)d_in[2];
    const int* hops = (const int*)d_in[3];
    float* out = (float*)d_out;

    float* partials = (float*)d_ws;                // 2 MB of ws

    k_colsum<<<dim3(CHUNKS * BN), dim3(256), 0, stream>>>(sent, mask, partials);
    k_final<<<dim3(BN), dim3(256), 0, stream>>>(sent, mask, Wm, hops, partials, out);
}

// Round 8
// 352.246 us; speedup vs baseline: 2.0581x; 1.0065x over previous
//
#include <hip/hip_runtime.h>

// MemN2N: B=64, S=4096, D=256, hops=3 (fp32).
// Algebraic reduction: softmax over a size-1 axis == 1 -> attention weights
// are the memory-validity mask, hop-independent:
//   x_b = sum_{s < len_b - 1} sentences[b,s,:]
//   out_b = q0_b + hops sequential adds of (x_b @ W)
// Round-3 lesson: no device-scope fences/atomics (cost ~400 us over 2k blocks).
// Round-4/5 lesson: resident blocks on a CU differ by multiples of 256, so
// ANY affine id->(b,c) map pins one coordinate per CU (256 = 0 mod 64 and
// mod 32) -> static imbalance ~2x mean. Fix: oversubscribe. CHUNKS=64 (64-row
// chunks, 4096 blocks = 16/CU vs 8 resident) -> dispatcher backfills as
// early-exit blocks vacate; heavy (low-c) chunks dispatch first. Tail
// granularity = one 64-row block (~2.5 us).

#define BN 64
#define SN 4096
#define DN 256
#define CHUNKS 64
#define CHUNK_ROWS (SN / CHUNKS) // 64

// Per-block valid-length compute. Mask dtype detected from word 0
// (len >= 2 guarantees first two elements are true):
//   1 -> int32 0/1; 0x3f800000 -> f32 1.0 (defensive); else bool bytes.
__device__ __forceinline__ int block_len(const unsigned int* __restrict__ mask_words,
                                         int b, int t, int* lred, int* len_sh) {
    const unsigned int w0 = mask_words[0];
    const int mode = (w0 == 1u) ? 0 : (w0 == 0x3f800000u) ? 1 : 2;
    const int wpr = (mode == 2) ? (SN / 4) : SN;
    const unsigned int* mrow = mask_words + (size_t)b * wpr;
    int lsum = 0;
    for (int i = t; i < wpr; i += 256) {
        const unsigned int w = mrow[i];
        lsum += (mode == 2) ? __popc(w) : (mode == 0 ? (int)w : (w != 0u ? 1 : 0));
    }
    #pragma unroll
    for (int off = 32; off > 0; off >>= 1)
        lsum += __shfl_down(lsum, off, 64);
    if ((t & 63) == 0) lred[t >> 6] = lsum;
    __syncthreads();
    if (t == 0) *len_sh = lred[0] + lred[1] + lred[2] + lred[3];
    __syncthreads();
    return *len_sh;
}

__global__ __launch_bounds__(256)
void k_colsum(const float* __restrict__ sent,
              const unsigned int* __restrict__ mask_words,
              float* __restrict__ partials) {      // [BN][CHUNKS][DN]
    const int id = blockIdx.x;                     // b fast, c slow:
    const int b = id & (BN - 1);                   // heavy (low-c) blocks
    const int c = id >> 6;                         // dispatch first
    const int t = threadIdx.x;
    __shared__ int lred[4];
    __shared__ int len_sh;
    __shared__ float4 red[256];

    const int limit = block_len(mask_words, b, t, lred, &len_sh) - 1;

    const int s0 = c * CHUNK_ROWS;
    const int d4 = (t & 63) * 4;                   // 4 contiguous columns
    const int g = t >> 6;                          // row group 0..3
    float4 acc = make_float4(0.f, 0.f, 0.f, 0.f);
    int nrows = limit - s0;
    if (nrows > CHUNK_ROWS) nrows = CHUNK_ROWS;
    if (nrows > 0) {
        const float* base = sent + ((size_t)b * SN + s0) * DN + d4;
        #pragma unroll 4
        for (int r = g; r < nrows; r += 4) {
            const float4 v = *reinterpret_cast<const float4*>(base + (size_t)r * DN);
            acc.x += v.x; acc.y += v.y; acc.z += v.z; acc.w += v.w;
        }
    }
    red[t] = acc;
    __syncthreads();
    if (t < 64) {
        const float4 a0 = red[t], a1 = red[64 + t], a2 = red[128 + t], a3 = red[192 + t];
        float4 o;
        o.x = a0.x + a1.x + a2.x + a3.x;
        o.y = a0.y + a1.y + a2.y + a3.y;
        o.z = a0.z + a1.z + a2.z + a3.z;
        o.w = a0.w + a1.w + a2.w + a3.w;
        reinterpret_cast<float4*>(partials + ((size_t)b * CHUNKS + c) * DN)[t] = o;
    }
}

__global__ __launch_bounds__(256)
void k_final(const float* __restrict__ sent,
             const unsigned int* __restrict__ mask_words,
             const float* __restrict__ Wm,
             const int* __restrict__ hops_ptr,
             const float* __restrict__ partials,
             float* __restrict__ out) {
    const int b = blockIdx.x;
    const int t = threadIdx.x;                     // == d, 256 threads
    __shared__ int lred[4];
    __shared__ int len_sh;
    __shared__ float xs[DN];

    const int limit = block_len(mask_words, b, t, lred, &len_sh) - 1;

    float x = 0.f;
    const float* p = partials + (size_t)b * CHUNKS * DN + t;
    #pragma unroll 8
    for (int k = 0; k < CHUNKS; ++k)
        x += p[k * DN];
    xs[t] = x;
    __syncthreads();
    const float q0 = sent[((size_t)b * SN + limit) * DN + t];
    float gv = 0.f;
    #pragma unroll 8
    for (int k = 0; k < DN; ++k)
        gv = fmaf(xs[k], Wm[k * DN + t], gv);
    const int hops = hops_ptr[0];
    float r = q0;
    for (int i = 0; i < hops; ++i)                 // match reference add order
        r += gv;
    out[b * DN + t] = r;
}

extern "C" void kernel_launch(void* const* d_in, const int* in_sizes, int n_in,
                              void* d_out, int out_size, void* d_ws, size_t ws_size,
                              hipStream_t stream) {
    const float* sent = (const float*)d_in[0];
    const unsigned int* mask = (const unsigned int*)d_in[1];
    const float* Wm = (const float*)d_in[2];
    const int* hops = (const int*)d_in[3];
    float* out = (float*)d_out;

    float* partials = (float*)d_ws;                // 4 MB of ws

    k_colsum<<<dim3(CHUNKS * BN), dim3(256), 0, stream>>>(sent, mask, partials);
    k_final<<<dim3(BN), dim3(256), 0, stream>>>(sent, mask, Wm, hops, partials, out);
}